// Round 1
// baseline (522.392 us; speedup 1.0000x reference)
//
#include <hip/hip_runtime.h>
#include <hip/hip_bf16.h>

#define GD 64
#define GC 256
#define GR 128

typedef unsigned short u16;
typedef unsigned int u32;
typedef short bf16x8 __attribute__((ext_vector_type(8)));
typedef float f32x4 __attribute__((ext_vector_type(4)));

__device__ __forceinline__ u16 f2bf_rne(float f) {
    u32 u = __builtin_bit_cast(u32, f);
    u = (u + 0x7FFFu + ((u >> 16) & 1u)) >> 16;
    return (u16)u;
}
__device__ __forceinline__ float bf2f(u16 h) {
    u32 u = ((u32)h) << 16;
    return __builtin_bit_cast(float, u);
}
__device__ __forceinline__ u16 f2bf_trunc_exact(float f) {
    // valid when f is already bf16-representable (max of bf16 values, or -inf)
    return (u16)(__builtin_bit_cast(u32, f) >> 16);
}

// ---------------------------------------------------------------- init grid
__global__ __launch_bounds__(256) void init_grid(uint4* __restrict__ g, int n16) {
    int i = blockIdx.x * 256 + threadIdx.x;
    if (i < n16) {
        uint4 v;
        v.x = v.y = v.z = v.w = 0xFF80FF80u;   // bf16 -inf pairs
        g[i] = v;
    }
}

// ---------------------------------------------------------------- scatter
__global__ __launch_bounds__(256) void scatter_feats(const float* __restrict__ feats,
        const int* __restrict__ coords, u16* __restrict__ grid, int n) {
    int t = blockIdx.x * 256 + threadIdx.x;
    int i = t >> 5;
    if (i >= n) return;
    int c8 = (t & 31) << 3;
    int ix = coords[3 * i], iy = coords[3 * i + 1], iz = coords[3 * i + 2];
    size_t cell = (size_t)((ix * GD + iy) * GD + iz);
    const float4* src = (const float4*)(feats + (size_t)i * GC + c8);
    float4 a = src[0], b = src[1];
    u32 p0 = (u32)f2bf_rne(a.x) | ((u32)f2bf_rne(a.y) << 16);
    u32 p1 = (u32)f2bf_rne(a.z) | ((u32)f2bf_rne(a.w) << 16);
    u32 p2 = (u32)f2bf_rne(b.x) | ((u32)f2bf_rne(b.y) << 16);
    u32 p3 = (u32)f2bf_rne(b.z) | ((u32)f2bf_rne(b.w) << 16);
    uint4 v = make_uint4(p0, p1, p2, p3);
    *(uint4*)(grid + cell * GC + c8) = v;
}

// ---------------------------------------------------------------- pool pass
// One workgroup per line (64 positions along the pooled axis); 256 threads = channels.
// In-place safe: each thread loads all 64 values of its (line, channel) into
// registers before any store; no other workgroup touches this line in this pass.
__global__ __launch_bounds__(256, 2) void pool_pass(u16* __restrict__ grid,
        int mulU, int mulV, int strideCell) {
    int b = blockIdx.x;
    int u = b >> 6, v = b & 63;
    int c = threadIdx.x;
    size_t base = (size_t)(u * mulU + v * mulV) * GC + c;
    size_t strideEl = (size_t)strideCell * GC;
    u16* __restrict__ q = grid + base;

    float vals[70];
#pragma unroll
    for (int j = 0; j < 3; j++) { vals[j] = -INFINITY; vals[67 + j] = -INFINITY; }
#pragma unroll
    for (int z = 0; z < 64; z++) vals[z + 3] = bf2f(q[(size_t)z * strideEl]);

#pragma unroll
    for (int z = 0; z < 64; z++) {
        float m = fmaxf(fmaxf(fmaxf(vals[z], vals[z + 1]), fmaxf(vals[z + 2], vals[z + 3])),
                        fmaxf(fmaxf(vals[z + 4], vals[z + 5]), vals[z + 6]));
        q[(size_t)z * strideEl] = f2bf_trunc_exact(m);
    }
}

// ---------------------------------------------------------------- GEMM1: H = relu(gather(Y) @ W1)
// Y[i][c] = grid[coords[i]][c] (bf16), W1: (256,128) f32 row-major.
// LDS holds W1^T bf16, XOR-swizzled in 16B chunks: exactly 64 KB.
__global__ __launch_bounds__(256, 2) void gemm1_kernel(const u16* __restrict__ grid,
        const int* __restrict__ coords, const float* __restrict__ W1,
        u16* __restrict__ H, int n) {
    __shared__ u16 w1t[GR * GC];   // [r(128)][k(256)] swizzled, 65536 B
    int tid = threadIdx.x;
    for (int e = tid; e < GC * GR; e += 256) {
        int k = e >> 7;        // 0..255 (W1 row)
        int r = e & 127;       // 0..127 (W1 col)
        int kc = k >> 3, kj = k & 7;
        w1t[r * GC + (((kc ^ (r & 7)) << 3) | kj)] = f2bf_rne(W1[e]);
    }
    __syncthreads();

    int wave = tid >> 6, lane = tid & 63;
    int m16 = lane & 15, quad = lane >> 4;
    int row_a = blockIdx.x * 64 + wave * 16 + m16;
    int ra = min(row_a, n - 1);
    int ix = coords[3 * ra], iy = coords[3 * ra + 1], iz = coords[3 * ra + 2];
    const u16* yrow = grid + (size_t)((ix * GD + iy) * GD + iz) * GC;

    bf16x8 a[8];
#pragma unroll
    for (int kk = 0; kk < 8; kk++)
        a[kk] = *(const bf16x8*)(yrow + kk * 32 + quad * 8);

    f32x4 acc[8];
#pragma unroll
    for (int t = 0; t < 8; t++) acc[t] = (f32x4){0.f, 0.f, 0.f, 0.f};

#pragma unroll
    for (int kk = 0; kk < 8; kk++) {
        int chunk = kk * 4 + quad;
#pragma unroll
        for (int t = 0; t < 8; t++) {
            int r = t * 16 + m16;
            bf16x8 bfrag = *(const bf16x8*)&w1t[r * GC + ((chunk ^ (r & 7)) << 3)];
            acc[t] = __builtin_amdgcn_mfma_f32_16x16x32_bf16(a[kk], bfrag, acc[t], 0, 0, 0);
        }
    }

    int row_d = blockIdx.x * 64 + wave * 16 + quad * 4;
#pragma unroll
    for (int t = 0; t < 8; t++) {
#pragma unroll
        for (int rr = 0; rr < 4; rr++) {
            int row = row_d + rr;
            if (row < n) {
                float hv = fmaxf(acc[t][rr], 0.0f);
                H[(size_t)row * GR + t * 16 + m16] = f2bf_rne(hv);
            }
        }
    }
}

// ---------------------------------------------------------------- GEMM2: out = feats * sigmoid(H @ W2)
// H: (N,128) bf16, W2: (128,256) f32 row-major.
__global__ __launch_bounds__(256, 2) void gemm2_kernel(const u16* __restrict__ H,
        const float* __restrict__ W2, const float* __restrict__ feats,
        float* __restrict__ out, int n) {
    __shared__ u16 w2t[GC * GR];   // [nn(256)][k(128)] swizzled, 65536 B
    int tid = threadIdx.x;
    for (int e = tid; e < GC * GR; e += 256) {
        int k = e >> 8;        // 0..127 (W2 row)
        int nn = e & 255;      // 0..255 (W2 col)
        int kc = k >> 3, kj = k & 7;
        w2t[nn * GR + (((kc ^ (nn & 7)) << 3) | kj)] = f2bf_rne(W2[e]);
    }
    __syncthreads();

    int wave = tid >> 6, lane = tid & 63;
    int m16 = lane & 15, quad = lane >> 4;
    int row_a = blockIdx.x * 64 + wave * 16 + m16;
    int ra = min(row_a, n - 1);
    const u16* hrow = H + (size_t)ra * GR;

    bf16x8 a[4];
#pragma unroll
    for (int kk = 0; kk < 4; kk++)
        a[kk] = *(const bf16x8*)(hrow + kk * 32 + quad * 8);

    f32x4 acc[16];
#pragma unroll
    for (int t = 0; t < 16; t++) acc[t] = (f32x4){0.f, 0.f, 0.f, 0.f};

#pragma unroll
    for (int kk = 0; kk < 4; kk++) {
        int chunk = kk * 4 + quad;
#pragma unroll
        for (int t = 0; t < 16; t++) {
            int nn = t * 16 + m16;
            bf16x8 bfrag = *(const bf16x8*)&w2t[nn * GR + ((chunk ^ (nn & 7)) << 3)];
            acc[t] = __builtin_amdgcn_mfma_f32_16x16x32_bf16(a[kk], bfrag, acc[t], 0, 0, 0);
        }
    }

    int row_d = blockIdx.x * 64 + wave * 16 + quad * 4;
#pragma unroll
    for (int t = 0; t < 16; t++) {
#pragma unroll
        for (int rr = 0; rr < 4; rr++) {
            int row = row_d + rr;
            if (row < n) {
                float z = acc[t][rr];
                float s = 1.0f / (1.0f + __expf(-z));
                size_t o = (size_t)row * GC + t * 16 + m16;
                out[o] = feats[o] * s;
            }
        }
    }
}

// ---------------------------------------------------------------- launch
extern "C" void kernel_launch(void* const* d_in, const int* in_sizes, int n_in,
                              void* d_out, int out_size, void* d_ws, size_t ws_size,
                              hipStream_t stream) {
    const float* feats = (const float*)d_in[0];
    const int* coords = (const int*)d_in[1];
    const float* W1 = (const float*)d_in[2];
    const float* W2 = (const float*)d_in[3];
    float* out = (float*)d_out;

    int n = in_sizes[1] / 3;                       // 100000 points

    u16* grid = (u16*)d_ws;                        // 64^3 * 256 bf16 = 134,217,728 B
    u16* H = (u16*)((char*)d_ws + (size_t)GD * GD * GD * GC * 2);  // N*128 bf16

    int n16 = GD * GD * GD * GC * 2 / 16;          // 8,388,608 uint4s
    init_grid<<<n16 / 256, 256, 0, stream>>>((uint4*)d_ws, n16);

    int st = n * 32;
    scatter_feats<<<(st + 255) / 256, 256, 0, stream>>>(feats, coords, grid, n);

    // separable 7-wide max pool, in place: z, then y, then x
    pool_pass<<<GD * GD, 256, 0, stream>>>(grid, GD * GD, GD, 1);   // z axis
    pool_pass<<<GD * GD, 256, 0, stream>>>(grid, GD * GD, 1, GD);   // y axis
    pool_pass<<<GD * GD, 256, 0, stream>>>(grid, GD, 1, GD * GD);   // x axis

    int wgs = (n + 63) / 64;
    gemm1_kernel<<<wgs, 256, 0, stream>>>(grid, coords, W1, H, n);
    gemm2_kernel<<<wgs, 256, 0, stream>>>(H, W2, feats, out, n);
}

// Round 2
// 380.490 us; speedup vs baseline: 1.3729x; 1.3729x over previous
//
#include <hip/hip_runtime.h>
#include <hip/hip_bf16.h>

#define GD 64
#define GC 256

typedef unsigned short u16;
typedef unsigned int u32;
typedef short bf16x8 __attribute__((ext_vector_type(8)));
typedef float f32x4 __attribute__((ext_vector_type(4)));

__device__ __forceinline__ u16 f2bf_rne(float f) {
    u32 u = __builtin_bit_cast(u32, f);
    u = (u + 0x7FFFu + ((u >> 16) & 1u)) >> 16;
    return (u16)u;
}

// ---------------------------------------------------------------- init grid
__global__ __launch_bounds__(256) void init_grid(uint4* __restrict__ g, int n16) {
    int i = blockIdx.x * 256 + threadIdx.x;
    if (i < n16) {
        uint4 v;
        v.x = v.y = v.z = v.w = 0xFF80FF80u;   // bf16 -inf pairs
        g[i] = v;
    }
}

// ---------------------------------------------------------------- scatter
__global__ __launch_bounds__(256) void scatter_feats(const float* __restrict__ feats,
        const int* __restrict__ coords, u16* __restrict__ grid, int n) {
    int t = blockIdx.x * 256 + threadIdx.x;
    int i = t >> 5;
    if (i >= n) return;
    int c8 = (t & 31) << 3;
    int ix = coords[3 * i], iy = coords[3 * i + 1], iz = coords[3 * i + 2];
    size_t cell = (size_t)((ix * GD + iy) * GD + iz);
    const float4* src = (const float4*)(feats + (size_t)i * GC + c8);
    float4 a = src[0], b = src[1];
    u32 p0 = (u32)f2bf_rne(a.x) | ((u32)f2bf_rne(a.y) << 16);
    u32 p1 = (u32)f2bf_rne(a.z) | ((u32)f2bf_rne(a.w) << 16);
    u32 p2 = (u32)f2bf_rne(b.x) | ((u32)f2bf_rne(b.y) << 16);
    u32 p3 = (u32)f2bf_rne(b.z) | ((u32)f2bf_rne(b.w) << 16);
    uint4 v = make_uint4(p0, p1, p2, p3);
    *(uint4*)(grid + cell * GC + c8) = v;
}

// ---------------------------------------------------------------- weight prep
// Bake pre-converted, pre-XOR-swizzled bf16 LDS images so gemm blocks stage
// with a flat vector copy (no per-block convert, no conflicted LDS writes).
// img1: 2 halves x [nn(64)][chunk(32)^swz][j(8)]  <- W1[k=chunk*8+j][h*64+nn]
// img2: 2 halves x [nn(128)][chunk(16)^swz][j(8)] <- W2[k=chunk*8+j][h*128+nn]
__global__ __launch_bounds__(256) void prep_weights(const float* __restrict__ W1,
        const float* __restrict__ W2, u16* __restrict__ img1, u16* __restrict__ img2) {
    int t = blockIdx.x * 256 + threadIdx.x;   // 0..65535
    if (t < 32768) {
        int h = t >> 14, nn = (t >> 8) & 63, chunk = (t >> 3) & 31, j = t & 7;
        int k = chunk * 8 + j;
        img1[(h << 14) + nn * 256 + (((chunk ^ (nn & 7)) << 3) | j)] =
            f2bf_rne(W1[k * 128 + h * 64 + nn]);
    } else {
        int t2 = t - 32768;
        int h = t2 >> 14, nn = (t2 >> 7) & 127, chunk = (t2 >> 3) & 15, j = t2 & 7;
        int k = chunk * 8 + j;
        img2[(h << 14) + nn * 128 + (((chunk ^ (nn & 7)) << 3) | j)] =
            f2bf_rne(W2[k * 256 + h * 128 + nn]);
    }
}

// ---------------------------------------------------------------- pool pass
// Rolling 7-window, 8 channels/thread (uint4), streaming in-place:
// store z after loading z+3; future loads are all > z, so no hazard.
// 32 threads/line (channel chunks), 8 lines/block, 512 blocks/pass.
__device__ __forceinline__ void unpack8(uint4 r, float* w) {
    u32 v[4] = {r.x, r.y, r.z, r.w};
#pragma unroll
    for (int i = 0; i < 4; i++) {
        w[2 * i]     = __builtin_bit_cast(float, v[i] << 16);
        w[2 * i + 1] = __builtin_bit_cast(float, v[i] & 0xFFFF0000u);
    }
}

__global__ __launch_bounds__(256) void pool_pass_v(u16* __restrict__ grid,
        int mulA, int mulB, int strideCell) {
    int chunk = threadIdx.x & 31;
    int L = blockIdx.x * 8 + (threadIdx.x >> 5);   // 0..4095
    int a = L >> 6, b = L & 63;
    size_t baseEl = ((size_t)a * mulA + (size_t)b * mulB) * GC + chunk * 8;
    size_t stepEl = (size_t)strideCell * GC;
    u16* p = grid + baseEl;

    float win[7][8];
#pragma unroll
    for (int s = 0; s < 7; s++)
#pragma unroll
        for (int c = 0; c < 8; c++) win[s][c] = -INFINITY;

#pragma unroll
    for (int t = 0; t < 3; t++) {   // preload in[0..2] -> slots 3..5
        uint4 r = *(const uint4*)(p + (size_t)t * stepEl);
        unpack8(r, win[t + 3]);
    }

#pragma unroll
    for (int z = 0; z < 64; z++) {
        int slot = (z + 6) % 7;     // in[z+3] replaces in[z-4]
        if (z + 3 < 64) {
            uint4 r = *(const uint4*)(p + (size_t)(z + 3) * stepEl);
            unpack8(r, win[slot]);
        } else {
#pragma unroll
            for (int c = 0; c < 8; c++) win[slot][c] = -INFINITY;
        }
        u32 q[4];
#pragma unroll
        for (int i = 0; i < 4; i++) {
            u32 halves[2];
#pragma unroll
            for (int hh = 0; hh < 2; hh++) {
                int c = 2 * i + hh;
                float m01 = fmaxf(win[0][c], win[1][c]);
                float m23 = fmaxf(win[2][c], win[3][c]);
                float m45 = fmaxf(win[4][c], win[5][c]);
                float m = fmaxf(fmaxf(m01, m23), fmaxf(m45, win[6][c]));
                halves[hh] = __builtin_bit_cast(u32, m);   // exact bf16 value
            }
            q[i] = (halves[0] >> 16) | (halves[1] & 0xFFFF0000u);
        }
        *(uint4*)(p + (size_t)z * stepEl) = make_uint4(q[0], q[1], q[2], q[3]);
    }
}

// ---------------------------------------------------------------- GEMM1 (half-N)
// block: 64 rows x 64 hidden cols (half h). LDS 32 KB staged flat from img1.
__global__ __launch_bounds__(256, 4) void gemm1_kernel(const u16* __restrict__ grid,
        const int* __restrict__ coords, const u16* __restrict__ img1,
        u16* __restrict__ H, int n, int nrb) {
    __shared__ __align__(16) u16 w1t[64 * 256];   // 32768 B; reused as hbuf
    int h = blockIdx.x >= nrb;
    int rb = blockIdx.x - (h ? nrb : 0);
    int tid = threadIdx.x;

    const uint4* src = (const uint4*)(img1 + (h << 14));
    uint4* dst = (uint4*)w1t;
#pragma unroll
    for (int i = 0; i < 8; i++) dst[i * 256 + tid] = src[i * 256 + tid];

    int wave = tid >> 6, lane = tid & 63, m16 = lane & 15, quad = lane >> 4;
    int row_a = rb * 64 + wave * 16 + m16;
    int ra = min(row_a, n - 1);
    int ix = coords[3 * ra], iy = coords[3 * ra + 1], iz = coords[3 * ra + 2];
    const u16* yrow = grid + (size_t)((ix * GD + iy) * GD + iz) * GC;
    bf16x8 afr[8];
#pragma unroll
    for (int kk = 0; kk < 8; kk++)
        afr[kk] = *(const bf16x8*)(yrow + kk * 32 + quad * 8);
    __syncthreads();

    f32x4 acc[4];
#pragma unroll
    for (int t = 0; t < 4; t++) acc[t] = (f32x4){0.f, 0.f, 0.f, 0.f};
#pragma unroll
    for (int kk = 0; kk < 8; kk++) {
        int chunk = kk * 4 + quad;
#pragma unroll
        for (int t = 0; t < 4; t++) {
            int r = t * 16 + m16;
            bf16x8 b = *(const bf16x8*)&w1t[r * 256 + ((chunk ^ (r & 7)) << 3)];
            acc[t] = __builtin_amdgcn_mfma_f32_16x16x32_bf16(afr[kk], b, acc[t], 0, 0, 0);
        }
    }
    __syncthreads();   // w1t dead; reuse as hbuf [row(64)][c8^swz][j]

    u16* hbuf = w1t;
#pragma unroll
    for (int t = 0; t < 4; t++) {
        int col = t * 16 + m16;
        int c8 = col >> 3, j = col & 7;
#pragma unroll
        for (int rr = 0; rr < 4; rr++) {
            int row_l = wave * 16 + quad * 4 + rr;
            float hv = fmaxf(acc[t][rr], 0.0f);
            hbuf[row_l * 64 + (((c8 ^ (row_l & 7)) << 3) | j)] = f2bf_rne(hv);
        }
    }
    __syncthreads();
#pragma unroll
    for (int i = 0; i < 2; i++) {
        int cid = i * 256 + tid;            // 0..511 chunks of 8
        int row_l = cid >> 3, c8 = cid & 7;
        int grow = rb * 64 + row_l;
        if (grow < n) {
            bf16x8 v = *(const bf16x8*)&hbuf[row_l * 64 + ((c8 ^ (row_l & 7)) << 3)];
            *(bf16x8*)&H[(size_t)grow * 128 + h * 64 + c8 * 8] = v;
        }
    }
}

// ---------------------------------------------------------------- GEMM2 (half-N)
// block: 64 rows x 128 out cols (half h). LDS 32 KB weights, then 64x140 f32
// transpose buffer for fully-coalesced float4 feats/out IO.
__global__ __launch_bounds__(256, 4) void gemm2_kernel(const u16* __restrict__ H,
        const u16* __restrict__ img2, const float* __restrict__ feats,
        float* __restrict__ out, int n, int nrb) {
    __shared__ __align__(16) char smem[64 * 140 * 4];   // 35840 B
    u16* w2t = (u16*)smem;          // 32768 B used
    float* zbuf = (float*)smem;     // 64 x 140 (pad keeps b128 16B-aligned, 2-way banks)
    int h = blockIdx.x >= nrb;
    int rb = blockIdx.x - (h ? nrb : 0);
    int tid = threadIdx.x;

    const uint4* src = (const uint4*)(img2 + (h << 14));
    uint4* dst = (uint4*)w2t;
#pragma unroll
    for (int i = 0; i < 8; i++) dst[i * 256 + tid] = src[i * 256 + tid];

    int wave = tid >> 6, lane = tid & 63, m16 = lane & 15, quad = lane >> 4;
    int row_a = rb * 64 + wave * 16 + m16;
    int ra = min(row_a, n - 1);
    const u16* hrow = H + (size_t)ra * 128;
    bf16x8 afr[4];
#pragma unroll
    for (int kk = 0; kk < 4; kk++)
        afr[kk] = *(const bf16x8*)(hrow + kk * 32 + quad * 8);
    __syncthreads();

    f32x4 acc[8];
#pragma unroll
    for (int t = 0; t < 8; t++) acc[t] = (f32x4){0.f, 0.f, 0.f, 0.f};
#pragma unroll
    for (int kk = 0; kk < 4; kk++) {
        int chunk = kk * 4 + quad;
#pragma unroll
        for (int t = 0; t < 8; t++) {
            int nn = t * 16 + m16;
            bf16x8 b = *(const bf16x8*)&w2t[nn * 128 + ((chunk ^ (nn & 7)) << 3)];
            acc[t] = __builtin_amdgcn_mfma_f32_16x16x32_bf16(afr[kk], b, acc[t], 0, 0, 0);
        }
    }
    __syncthreads();   // w2t dead; write logits into zbuf

#pragma unroll
    for (int t = 0; t < 8; t++) {
        int col = t * 16 + m16;
#pragma unroll
        for (int rr = 0; rr < 4; rr++) {
            int row_l = wave * 16 + quad * 4 + rr;
            zbuf[row_l * 140 + col] = acc[t][rr];
        }
    }
    __syncthreads();
#pragma unroll
    for (int i = 0; i < 8; i++) {
        int f = i * 256 + tid;              // 0..2047 float4s
        int row_l = f >> 5, c4 = f & 31;
        int grow = rb * 64 + row_l;
        if (grow < n) {
            f32x4 z = *(const f32x4*)&zbuf[row_l * 140 + c4 * 4];
            size_t o = (size_t)grow * 256 + h * 128 + c4 * 4;
            f32x4 ft = *(const f32x4*)&feats[o];
            f32x4 r;
#pragma unroll
            for (int c = 0; c < 4; c++)
                r[c] = ft[c] / (1.0f + __expf(-z[c]));
            *(f32x4*)&out[o] = r;
        }
    }
}

// ---------------------------------------------------------------- launch
extern "C" void kernel_launch(void* const* d_in, const int* in_sizes, int n_in,
                              void* d_out, int out_size, void* d_ws, size_t ws_size,
                              hipStream_t stream) {
    const float* feats = (const float*)d_in[0];
    const int* coords = (const int*)d_in[1];
    const float* W1 = (const float*)d_in[2];
    const float* W2 = (const float*)d_in[3];
    float* out = (float*)d_out;

    int n = in_sizes[1] / 3;                       // 100000 points

    size_t grid_bytes = (size_t)GD * GD * GD * GC * 2;          // 134,217,728
    u16* grid = (u16*)d_ws;
    u16* H = (u16*)((char*)d_ws + grid_bytes);                  // n*128 bf16
    u16* img1 = (u16*)((char*)d_ws + grid_bytes + (size_t)n * 128 * 2);
    u16* img2 = img1 + 32768;                                   // 2x16384 each

    int n16 = (int)(grid_bytes / 16);
    init_grid<<<n16 / 256, 256, 0, stream>>>((uint4*)d_ws, n16);

    prep_weights<<<256, 256, 0, stream>>>(W1, W2, img1, img2);

    scatter_feats<<<(n * 32 + 255) / 256, 256, 0, stream>>>(feats, coords, grid, n);

    // separable 7-wide max pool, in place, vectorized: z, y, x
    pool_pass_v<<<512, 256, 0, stream>>>(grid, GD * GD, GD, 1);        // z
    pool_pass_v<<<512, 256, 0, stream>>>(grid, GD * GD, 1, GD);        // y
    pool_pass_v<<<512, 256, 0, stream>>>(grid, GD, 1, GD * GD);        // x

    int nrb = (n + 63) / 64;
    gemm1_kernel<<<2 * nrb, 256, 0, stream>>>(grid, coords, img1, H, n, nrb);
    gemm2_kernel<<<2 * nrb, 256, 0, stream>>>(H, img2, feats, out, n, nrb);
}